// Round 1
// baseline (98.603 us; speedup 1.0000x reference)
//
#include <hip/hip_runtime.h>

#define BB 32
#define CC 512
#define LL 4096
#define NB 16
#define EPSF 1e-8f

// ws layout (floats):
//   [0, 16384)            g[B*C]
//   [16384, 16384+131072) cos[B*L]
//   then 512 pmin, 512 pmax

// ---------------- Kernel 1: g[b,c] = mean_l x[b,c,l] ----------------
// One wave per row (4096 contiguous floats). 4 waves/block -> 4 rows/block.
__global__ void k_rowmean(const float* __restrict__ x, float* __restrict__ g) {
    const int wave = threadIdx.x >> 6;
    const int lane = threadIdx.x & 63;
    const int row  = blockIdx.x * 4 + wave;            // row in [0, B*C)
    const float4* xr = (const float4*)(x + (size_t)row * LL);
    float s = 0.f;
#pragma unroll
    for (int it = 0; it < 16; ++it) {                  // 16*64*4 = 4096
        float4 v = xr[it * 64 + lane];
        s += (v.x + v.y) + (v.z + v.w);
    }
#pragma unroll
    for (int off = 32; off; off >>= 1) s += __shfl_down(s, off, 64);
    if (lane == 0) g[row] = s * (1.0f / LL);
}

// ---------------- Kernel 2: cos[b,l] + per-block min/max ----------------
// blockIdx = b*16 + ltile ; thread owns one l. Loop over c (coalesced 4B/lane,
// g[c] wave-uniform). Accumulate dot, sum(x^2), sum(g^2) in registers.
__global__ void k_cos(const float* __restrict__ x, const float* __restrict__ g,
                      float* __restrict__ cosv,
                      float* __restrict__ pmin, float* __restrict__ pmax) {
    const int b = blockIdx.x >> 4;
    const int l = ((blockIdx.x & 15) << 8) + threadIdx.x;
    const float* xb = x + (size_t)b * CC * LL + l;
    const float* gb = g + b * CC;

    float dot = 0.f, ss = 0.f, gg = 0.f;
#pragma unroll 8
    for (int c = 0; c < CC; ++c) {
        float xv = xb[(size_t)c * LL];
        float gv = gb[c];
        dot = fmaf(xv, gv, dot);
        ss  = fmaf(xv, xv, ss);
        gg  = fmaf(gv, gv, gg);
    }
    float cs = dot / fmaxf(sqrtf(ss) * sqrtf(gg), EPSF);
    cosv[(b << 12) + ((blockIdx.x & 15) << 8) + threadIdx.x] = cs;

    // block-level min/max reduction
    float mn = cs, mx = cs;
#pragma unroll
    for (int off = 32; off; off >>= 1) {
        mn = fminf(mn, __shfl_down(mn, off, 64));
        mx = fmaxf(mx, __shfl_down(mx, off, 64));
    }
    __shared__ float smn[4], smx[4];
    const int wave = threadIdx.x >> 6, lane = threadIdx.x & 63;
    if (lane == 0) { smn[wave] = mn; smx[wave] = mx; }
    __syncthreads();
    if (threadIdx.x == 0) {
        mn = fminf(fminf(smn[0], smn[1]), fminf(smn[2], smn[3]));
        mx = fmaxf(fmaxf(smx[0], smx[1]), fmaxf(smx[2], smx[3]));
        pmin[blockIdx.x] = mn;
        pmax[blockIdx.x] = mx;
    }
}

// ---------------- Kernel 3: histogram per b, normalize, broadcast ----------------
// 32 blocks (one per b) x 256 threads. Each block redundantly reduces the
// 512 min/max partials (tiny, L2-hot), then bins its 4096 cos values.
__global__ void k_hist(const float* __restrict__ cosv,
                       const float* __restrict__ pmin, const float* __restrict__ pmax,
                       float* __restrict__ out) {
    const int b = blockIdx.x;
    const int wave = threadIdx.x >> 6, lane = threadIdx.x & 63;

    float mn = fminf(pmin[threadIdx.x], pmin[threadIdx.x + 256]);
    float mx = fmaxf(pmax[threadIdx.x], pmax[threadIdx.x + 256]);
#pragma unroll
    for (int off = 32; off; off >>= 1) {
        mn = fminf(mn, __shfl_down(mn, off, 64));
        mx = fmaxf(mx, __shfl_down(mx, off, 64));
    }
    __shared__ float smn[4], smx[4];
    if (lane == 0) { smn[wave] = mn; smx[wave] = mx; }
    __syncthreads();
    mn = fminf(fminf(smn[0], smn[1]), fminf(smn[2], smn[3]));
    mx = fmaxf(fmaxf(smx[0], smx[1]), fmaxf(smx[2], smx[3]));
    const float range = mx - mn;

    float bins[NB];
#pragma unroll
    for (int n = 0; n < NB; ++n) bins[n] = 0.f;

    const float* cb = cosv + (b << 12);
    for (int l = threadIdx.x; l < LL; l += 256) {
        float s = cb[l];
#pragma unroll
        for (int n = 0; n < NB; ++n) {
            float lev = mn + ((float)n * range) / 15.0f;   // match ref order of ops
            float d = fabsf(s - lev);
            bins[n] += (d < 0.03125f) ? (1.0f - d) : 0.f;
        }
    }
    // reduce 16 bins across block
#pragma unroll
    for (int n = 0; n < NB; ++n) {
#pragma unroll
        for (int off = 32; off; off >>= 1) bins[n] += __shfl_down(bins[n], off, 64);
    }
    __shared__ float sb[4][NB];
    if (lane == 0) {
#pragma unroll
        for (int n = 0; n < NB; ++n) sb[wave][n] = bins[n];
    }
    __syncthreads();
    __shared__ float colsum[NB];
    if (threadIdx.x < NB) {
        const int n = threadIdx.x;
        colsum[n] = sb[0][n] + sb[1][n] + sb[2][n] + sb[3][n];
    }
    __syncthreads();
    float total = 0.f;
#pragma unroll
    for (int n = 0; n < NB; ++n) total += colsum[n];
    // out[b, n, j] = colsum[n]/total ; flat = b*512 + n*32 + j ; 512 writes/block
    {
        const int i0 = threadIdx.x;
        out[b * (NB * 32) + i0]       = colsum[i0 >> 5] / total;
        out[b * (NB * 32) + i0 + 256] = colsum[(i0 + 256) >> 5] / total;
    }
}

extern "C" void kernel_launch(void* const* d_in, const int* in_sizes, int n_in,
                              void* d_out, int out_size, void* d_ws, size_t ws_size,
                              hipStream_t stream) {
    const float* x = (const float*)d_in[0];
    float* out = (float*)d_out;
    float* ws  = (float*)d_ws;

    float* g    = ws;                    // 16384 floats
    float* cosv = ws + 16384;            // 131072 floats
    float* pmin = ws + 16384 + 131072;   // 512 floats
    float* pmax = pmin + 512;            // 512 floats

    k_rowmean<<<(BB * CC) / 4, 256, 0, stream>>>(x, g);
    k_cos<<<BB * (LL / 256), 256, 0, stream>>>(x, g, cosv, pmin, pmax);
    k_hist<<<BB, 256, 0, stream>>>(cosv, pmin, pmax, out);
}

// Round 2
// 96.747 us; speedup vs baseline: 1.0192x; 1.0192x over previous
//
#include <hip/hip_runtime.h>

#define BB 32
#define CC 512
#define LL 4096
#define NB 16
#define EPSF 1e-8f

// ws layout (floats):
//   [0, 16384)            g[B*C]
//   [16384, 16384+131072) cos[B*L]
//   then 512 pmin, 512 pmax

// ---------------- Kernel 1: g[b,c] = mean_l x[b,c,l] ----------------
// One wave per row (4096 contiguous floats), ASCENDING address order.
__global__ void k_rowmean(const float* __restrict__ x, float* __restrict__ g) {
    const int wave = threadIdx.x >> 6;
    const int lane = threadIdx.x & 63;
    const int row  = blockIdx.x * 4 + wave;            // row in [0, B*C)
    const float4* xr = (const float4*)(x + (size_t)row * LL);
    float s = 0.f;
#pragma unroll
    for (int it = 0; it < 16; ++it) {                  // 16*64*4 = 4096
        float4 v = xr[it * 64 + lane];
        s += (v.x + v.y) + (v.z + v.w);
    }
#pragma unroll
    for (int off = 32; off; off >>= 1) s += __shfl_down(s, off, 64);
    if (lane == 0) g[row] = s * (1.0f / LL);
}

// ---------------- Kernel 2: cos[b,l] + per-block min/max ----------------
// DESCENDING address order: b=31 first, c-loop descending — consumes the
// L3-resident tail left by k_rowmean's ascending stream.
__global__ void k_cos(const float* __restrict__ x, const float* __restrict__ g,
                      float* __restrict__ cosv,
                      float* __restrict__ pmin, float* __restrict__ pmax) {
    const int b     = (BB - 1) - (blockIdx.x >> 4);
    const int ltile = 15 - (blockIdx.x & 15);
    const int l     = (ltile << 8) + threadIdx.x;
    const float* xb = x + (size_t)b * CC * LL + l;
    const float* gb = g + b * CC;

    float dot = 0.f, ss = 0.f, gg = 0.f;
#pragma unroll 16
    for (int c = CC - 1; c >= 0; --c) {
        float xv = xb[(size_t)c * LL];
        float gv = gb[c];
        dot = fmaf(xv, gv, dot);
        ss  = fmaf(xv, xv, ss);
        gg  = fmaf(gv, gv, gg);
    }
    float cs = dot / fmaxf(sqrtf(ss) * sqrtf(gg), EPSF);
    cosv[(b << 12) + l] = cs;

    // block-level min/max reduction
    float mn = cs, mx = cs;
#pragma unroll
    for (int off = 32; off; off >>= 1) {
        mn = fminf(mn, __shfl_down(mn, off, 64));
        mx = fmaxf(mx, __shfl_down(mx, off, 64));
    }
    __shared__ float smn[4], smx[4];
    const int wave = threadIdx.x >> 6, lane = threadIdx.x & 63;
    if (lane == 0) { smn[wave] = mn; smx[wave] = mx; }
    __syncthreads();
    if (threadIdx.x == 0) {
        mn = fminf(fminf(smn[0], smn[1]), fminf(smn[2], smn[3]));
        mx = fmaxf(fmaxf(smx[0], smx[1]), fmaxf(smx[2], smx[3]));
        pmin[blockIdx.x] = mn;
        pmax[blockIdx.x] = mx;
    }
}

// ---------------- Kernel 3: histogram per b, normalize, broadcast ----------------
__global__ void k_hist(const float* __restrict__ cosv,
                       const float* __restrict__ pmin, const float* __restrict__ pmax,
                       float* __restrict__ out) {
    const int b = blockIdx.x;
    const int wave = threadIdx.x >> 6, lane = threadIdx.x & 63;

    float mn = fminf(pmin[threadIdx.x], pmin[threadIdx.x + 256]);
    float mx = fmaxf(pmax[threadIdx.x], pmax[threadIdx.x + 256]);
#pragma unroll
    for (int off = 32; off; off >>= 1) {
        mn = fminf(mn, __shfl_down(mn, off, 64));
        mx = fmaxf(mx, __shfl_down(mx, off, 64));
    }
    __shared__ float smn[4], smx[4];
    if (lane == 0) { smn[wave] = mn; smx[wave] = mx; }
    __syncthreads();
    mn = fminf(fminf(smn[0], smn[1]), fminf(smn[2], smn[3]));
    mx = fmaxf(fmaxf(smx[0], smx[1]), fmaxf(smx[2], smx[3]));
    const float range = mx - mn;

    float bins[NB];
#pragma unroll
    for (int n = 0; n < NB; ++n) bins[n] = 0.f;

    const float* cb = cosv + (b << 12);
    for (int l = threadIdx.x; l < LL; l += 256) {
        float s = cb[l];
#pragma unroll
        for (int n = 0; n < NB; ++n) {
            float lev = mn + ((float)n * range) / 15.0f;   // match ref order of ops
            float d = fabsf(s - lev);
            bins[n] += (d < 0.03125f) ? (1.0f - d) : 0.f;
        }
    }
#pragma unroll
    for (int n = 0; n < NB; ++n) {
#pragma unroll
        for (int off = 32; off; off >>= 1) bins[n] += __shfl_down(bins[n], off, 64);
    }
    __shared__ float sb[4][NB];
    if (lane == 0) {
#pragma unroll
        for (int n = 0; n < NB; ++n) sb[wave][n] = bins[n];
    }
    __syncthreads();
    __shared__ float colsum[NB];
    if (threadIdx.x < NB) {
        const int n = threadIdx.x;
        colsum[n] = sb[0][n] + sb[1][n] + sb[2][n] + sb[3][n];
    }
    __syncthreads();
    float total = 0.f;
#pragma unroll
    for (int n = 0; n < NB; ++n) total += colsum[n];
    {
        const int i0 = threadIdx.x;
        out[b * (NB * 32) + i0]       = colsum[i0 >> 5] / total;
        out[b * (NB * 32) + i0 + 256] = colsum[(i0 + 256) >> 5] / total;
    }
}

extern "C" void kernel_launch(void* const* d_in, const int* in_sizes, int n_in,
                              void* d_out, int out_size, void* d_ws, size_t ws_size,
                              hipStream_t stream) {
    const float* x = (const float*)d_in[0];
    float* out = (float*)d_out;
    float* ws  = (float*)d_ws;

    float* g    = ws;                    // 16384 floats
    float* cosv = ws + 16384;            // 131072 floats
    float* pmin = ws + 16384 + 131072;   // 512 floats
    float* pmax = pmin + 512;            // 512 floats

    k_rowmean<<<(BB * CC) / 4, 256, 0, stream>>>(x, g);
    k_cos<<<BB * (LL / 256), 256, 0, stream>>>(x, g, cosv, pmin, pmax);
    k_hist<<<BB, 256, 0, stream>>>(cosv, pmin, pmax, out);
}

// Round 3
// 66.000 us; speedup vs baseline: 1.4940x; 1.4659x over previous
//
#include <hip/hip_runtime.h>

#define BB 32
#define CC 512
#define LL 4096
#define NB 16
#define EPSF 1e-8f

// ---------------- fused main kernel: g + partial dot/ss, ONE read of x ----
// grid = 32 b x 16 chunks = 512 blocks (2/CU). chunk = 32 channels,
// 8 stages x 4 rows. Per stage: wave w loads row w (16 float4/lane) ->
// row-sum in regs (g) -> spill to LDS -> issue next stage's loads ->
// dot/ss pass from LDS into 32 accum regs.
template<bool ATOMIC>
__global__ __launch_bounds__(256, 2)
void k_main(const float* __restrict__ x, float* __restrict__ g,
            float* __restrict__ pd, float* __restrict__ ps) {
    __shared__ float lds[4 * LL];          // 64 KB
    __shared__ float sgv[4];
    const int tid = threadIdx.x;
    const int w = tid >> 6, lane = tid & 63;
    const int b  = blockIdx.x >> 4;
    const int c0 = (blockIdx.x & 15) * 32;
    const float* xb = x + ((size_t)b * CC + c0 + w) * LL;   // wave w's stage-0 row

    float dot[16], ss[16];
#pragma unroll
    for (int j = 0; j < 16; ++j) { dot[j] = 0.f; ss[j] = 0.f; }

    float4 v[16];
    {
        const float4* row = (const float4*)xb;
#pragma unroll
        for (int i = 0; i < 16; ++i) v[i] = row[i * 64 + lane];
    }
    for (int st = 0; st < 8; ++st) {
        // row sum (from regs, free) -> g
        float s = 0.f;
#pragma unroll
        for (int i = 0; i < 16; ++i) s += (v[i].x + v[i].y) + (v[i].z + v[i].w);
#pragma unroll
        for (int off = 32; off; off >>= 1) s += __shfl_down(s, off, 64);
        __syncthreads();                    // prev stage's LDS/sgv reads done
        if (lane == 0) {
            float gv = s * (1.0f / LL);
            sgv[w] = gv;
            g[b * CC + c0 + st * 4 + w] = gv;
        }
        float4* lrow = (float4*)&lds[w * LL];
#pragma unroll
        for (int i = 0; i < 16; ++i) lrow[i * 64 + lane] = v[i];
        __syncthreads();                    // LDS + sgv visible
        // issue next stage's global loads BEFORE the dot pass (pipeline)
        if (st < 7) {
            const float4* row = (const float4*)(xb + (size_t)(st + 1) * 4 * LL);
#pragma unroll
            for (int i = 0; i < 16; ++i) v[i] = row[i * 64 + lane];
        }
        // dot/ss pass: thread owns l = tid + 256j; lds reads 2-way (free)
#pragma unroll
        for (int c = 0; c < 4; ++c) {
            const float gv = sgv[c];
            const float* lc = &lds[c * LL];
#pragma unroll
            for (int j = 0; j < 16; ++j) {
                float f = lc[j * 256 + tid];
                dot[j] = fmaf(f, gv, dot[j]);
                ss[j]  = fmaf(f, f, ss[j]);
            }
        }
    }
    if constexpr (ATOMIC) {
#pragma unroll
        for (int j = 0; j < 16; ++j) {
            atomicAdd(&pd[(b << 12) + j * 256 + tid], dot[j]);
            atomicAdd(&ps[(b << 12) + j * 256 + tid], ss[j]);
        }
    } else {
#pragma unroll
        for (int j = 0; j < 16; ++j) {
            pd[((size_t)blockIdx.x << 12) + j * 256 + tid] = dot[j];
            ps[((size_t)blockIdx.x << 12) + j * 256 + tid] = ss[j];
        }
    }
}

__global__ void k_zero(float* __restrict__ p) {
    ((float4*)p)[blockIdx.x * 256 + threadIdx.x] = make_float4(0.f, 0.f, 0.f, 0.f);
}

// ---------------- reduce: fold chunk partials -> cos + min/max partials ----
template<bool ATOMIC>
__global__ void k_reduce(const float* __restrict__ g,
                         const float* __restrict__ pd, const float* __restrict__ ps,
                         float* __restrict__ cosv,
                         float* __restrict__ pmin, float* __restrict__ pmax) {
    const int tid = threadIdx.x;
    const int w = tid >> 6, lane = tid & 63;
    const int b  = blockIdx.x >> 4;
    const int lt = blockIdx.x & 15;

    // gn = sqrt(sum_c g^2) (block-redundant, L2-hot, trivial)
    float a0 = g[b * CC + tid], a1 = g[b * CC + 256 + tid];
    float sq = fmaf(a0, a0, a1 * a1);
#pragma unroll
    for (int off = 32; off; off >>= 1) sq += __shfl_down(sq, off, 64);
    __shared__ float sw[4];
    if (lane == 0) sw[w] = sq;
    __syncthreads();
    const float gn = sqrtf((sw[0] + sw[1]) + (sw[2] + sw[3]));

    const int l = lt * 256 + tid;
    float pdv = 0.f, psv = 0.f;
    if constexpr (ATOMIC) {
        pdv = pd[((size_t)b << 12) + l];
        psv = ps[((size_t)b << 12) + l];
    } else {
#pragma unroll
        for (int ch = 0; ch < 16; ++ch) {
            pdv += pd[(((size_t)b * 16 + ch) << 12) + l];
            psv += ps[(((size_t)b * 16 + ch) << 12) + l];
        }
    }
    float cs = pdv / fmaxf(sqrtf(psv) * gn, EPSF);
    cosv[(b << 12) + l] = cs;

    float mn = cs, mx = cs;
#pragma unroll
    for (int off = 32; off; off >>= 1) {
        mn = fminf(mn, __shfl_down(mn, off, 64));
        mx = fmaxf(mx, __shfl_down(mx, off, 64));
    }
    __shared__ float smn[4], smx[4];
    if (lane == 0) { smn[w] = mn; smx[w] = mx; }
    __syncthreads();
    if (tid == 0) {
        pmin[blockIdx.x] = fminf(fminf(smn[0], smn[1]), fminf(smn[2], smn[3]));
        pmax[blockIdx.x] = fmaxf(fmaxf(smx[0], smx[1]), fmaxf(smx[2], smx[3]));
    }
}

// ---------------- histogram per b, normalize, broadcast ----------------
__global__ void k_hist(const float* __restrict__ cosv,
                       const float* __restrict__ pmin, const float* __restrict__ pmax,
                       float* __restrict__ out) {
    const int b = blockIdx.x;
    const int wave = threadIdx.x >> 6, lane = threadIdx.x & 63;

    float mn = fminf(pmin[threadIdx.x], pmin[threadIdx.x + 256]);
    float mx = fmaxf(pmax[threadIdx.x], pmax[threadIdx.x + 256]);
#pragma unroll
    for (int off = 32; off; off >>= 1) {
        mn = fminf(mn, __shfl_down(mn, off, 64));
        mx = fmaxf(mx, __shfl_down(mx, off, 64));
    }
    __shared__ float smn[4], smx[4];
    if (lane == 0) { smn[wave] = mn; smx[wave] = mx; }
    __syncthreads();
    mn = fminf(fminf(smn[0], smn[1]), fminf(smn[2], smn[3]));
    mx = fmaxf(fmaxf(smx[0], smx[1]), fmaxf(smx[2], smx[3]));
    const float range = mx - mn;

    float bins[NB];
#pragma unroll
    for (int n = 0; n < NB; ++n) bins[n] = 0.f;

    const float* cb = cosv + (b << 12);
    for (int l = threadIdx.x; l < LL; l += 256) {
        float s = cb[l];
#pragma unroll
        for (int n = 0; n < NB; ++n) {
            float lev = mn + ((float)n * range) / 15.0f;   // match ref order of ops
            float d = fabsf(s - lev);
            bins[n] += (d < 0.03125f) ? (1.0f - d) : 0.f;
        }
    }
#pragma unroll
    for (int n = 0; n < NB; ++n) {
#pragma unroll
        for (int off = 32; off; off >>= 1) bins[n] += __shfl_down(bins[n], off, 64);
    }
    __shared__ float sb[4][NB];
    if (lane == 0) {
#pragma unroll
        for (int n = 0; n < NB; ++n) sb[wave][n] = bins[n];
    }
    __syncthreads();
    __shared__ float colsum[NB];
    if (threadIdx.x < NB) {
        const int n = threadIdx.x;
        colsum[n] = sb[0][n] + sb[1][n] + sb[2][n] + sb[3][n];
    }
    __syncthreads();
    float total = 0.f;
#pragma unroll
    for (int n = 0; n < NB; ++n) total += colsum[n];
    {
        const int i0 = threadIdx.x;
        out[b * (NB * 32) + i0]       = colsum[i0 >> 5] / total;
        out[b * (NB * 32) + i0 + 256] = colsum[(i0 + 256) >> 5] / total;
    }
}

extern "C" void kernel_launch(void* const* d_in, const int* in_sizes, int n_in,
                              void* d_out, int out_size, void* d_ws, size_t ws_size,
                              hipStream_t stream) {
    const float* x = (const float*)d_in[0];
    float* out = (float*)d_out;
    float* ws  = (float*)d_ws;

    float* g    = ws;                      // 16384 floats
    float* cosv = ws + 16384;              // 131072 floats
    float* pmin = ws + 16384 + 131072;     // 512
    float* pmax = pmin + 512;              // 512
    float* p0   = pmax + 512;              // partials start @ float 148480

    const bool part = ws_size >= (size_t)(148480 + 2 * 2097152) * 4;
    if (part) {
        float* pd = p0;
        float* ps = p0 + 2097152;
        k_main<false><<<512, 256, 0, stream>>>(x, g, pd, ps);
        k_reduce<false><<<512, 256, 0, stream>>>(g, pd, ps, cosv, pmin, pmax);
    } else {
        float* dacc = p0;                  // 131072
        float* sacc = p0 + 131072;         // 131072
        k_zero<<<256, 256, 0, stream>>>(dacc);   // zeros dacc+sacc (262144 floats)
        k_main<true><<<512, 256, 0, stream>>>(x, g, dacc, sacc);
        k_reduce<true><<<512, 256, 0, stream>>>(g, dacc, sacc, cosv, pmin, pmax);
    }
    k_hist<<<32, 256, 0, stream>>>(cosv, pmin, pmax, out);
}